// Round 7
// baseline (475.342 us; speedup 1.0000x reference)
//
#include <hip/hip_runtime.h>
#include <hip/hip_bf16.h>

#define B_    16
#define L_    2048
#define BL    (B_ * L_)
#define DM    64
#define DS    16
#define HD    16
#define DI    128
#define NH    8
#define INW   296
#define XBC_  160
#define CONVK 4
#define NAGG  10
#define NACT  6
#define CS    32          // chunk size for scan
#define NCK   (L_ / CS)   // 64 chunks

// ---------------------------------------------------------------------------
// Kernel A: embedding gather + proj_in (80 x 64) + bias -> x (BL, 64)
// ---------------------------------------------------------------------------
__global__ __launch_bounds__(256) void k_embed(
    const int* __restrict__ aggs, const float* __restrict__ pegE,
    const float* __restrict__ countE, const float* __restrict__ topE,
    const float* __restrict__ W, const float* __restrict__ bias,
    float* __restrict__ x) {
  __shared__ float e[16][80];
  const int row0 = blockIdx.x * 16;
  const int t = threadIdx.x;
  if (t < 160) {
    int r = t / 10, i = t % 10;
    const float* tab = (i == 0 || i == 1 || i == 9) ? pegE
                       : (i >= 5 && i <= 7)         ? topE
                                                    : countE;
    int idx = aggs[(row0 + r) * NAGG + i];
    const float* src = tab + idx * 8;
#pragma unroll
    for (int j = 0; j < 8; ++j) e[r][i * 8 + j] = src[j];
  }
  __syncthreads();
  const int c = t & 63, rg = t >> 6;
  float acc[4] = {0.f, 0.f, 0.f, 0.f};
  const float* Wc = W + c;
  for (int k = 0; k < 80; k += 4) {
    float w0 = Wc[k * 64], w1 = Wc[(k + 1) * 64], w2 = Wc[(k + 2) * 64],
          w3 = Wc[(k + 3) * 64];
#pragma unroll
    for (int j = 0; j < 4; ++j) {
      float4 ev = *(const float4*)&e[rg + j * 4][k];
      acc[j] = fmaf(ev.x, w0, acc[j]);
      acc[j] = fmaf(ev.y, w1, acc[j]);
      acc[j] = fmaf(ev.z, w2, acc[j]);
      acc[j] = fmaf(ev.w, w3, acc[j]);
    }
  }
  float bc = bias[c];
#pragma unroll
  for (int j = 0; j < 4; ++j) x[(size_t)(row0 + rg + j * 4) * 64 + c] = acc[j] + bc;
}

// ---------------------------------------------------------------------------
// Kernel B (fused): RMSNorm + in_proj (64x296) + causal conv(K=4) + SiLU
//                   + RoPE + dt/a precompute.
// Per block: 16 output rows; 19 LDS rows (3-row conv halo recomputed).
// Halo rows at sequence start are zeroed -> matches JAX zero padding.
// ---------------------------------------------------------------------------
__global__ __launch_bounds__(256) void k_fused_in(
    const float* __restrict__ x, const float* __restrict__ rms_w,
    const float* __restrict__ W, const float* __restrict__ conv_w,
    const float* __restrict__ conv_b, const float* __restrict__ dt_bias,
    const float* __restrict__ A_log, float* __restrict__ z,
    float* __restrict__ xs, float* __restrict__ Bmr, float* __restrict__ Cmr,
    float2* __restrict__ ahd) {
  __shared__ float xn[19][64];
  __shared__ float s_xbc[19][160];
  __shared__ float s_cw[640];
  __shared__ float bcv[16][32];
  const int row0 = blockIdx.x * 16;
  const int t = threadIdx.x;
  const bool atStart = (row0 & (L_ - 1)) == 0;
  // stage x rows row0-3 .. row0+15  (lds row lr <-> global row row0+lr-3)
  for (int idx = t; idx < 19 * 64; idx += 256) {
    int lr = idx >> 6, c = idx & 63;
    xn[lr][c] = (atStart && lr < 3) ? 0.f
                                    : x[(size_t)(row0 + lr - 3) * 64 + c];
  }
  for (int idx = t; idx < 640; idx += 256) s_cw[idx] = conv_w[idx];
  __syncthreads();
  // RMSNorm in place: 16 threads per row
  {
    int r = t >> 4, l = t & 15;
    float4 v = *(const float4*)&xn[r][l * 4];
    float ss = v.x * v.x + v.y * v.y + v.z * v.z + v.w * v.w;
#pragma unroll
    for (int o = 1; o < 16; o <<= 1) ss += __shfl_xor(ss, o, 16);
    float inv = rsqrtf(ss * (1.0f / 64.0f) + 1e-6f);
    xn[r][l * 4 + 0] = v.x * inv * rms_w[l * 4 + 0];
    xn[r][l * 4 + 1] = v.y * inv * rms_w[l * 4 + 1];
    xn[r][l * 4 + 2] = v.z * inv * rms_w[l * 4 + 2];
    xn[r][l * 4 + 3] = v.w * inv * rms_w[l * 4 + 3];
    if (t < 48) {  // rows 16..18
      int r2 = 16 + (t >> 4);
      float4 v2 = *(const float4*)&xn[r2][l * 4];
      float s2 = v2.x * v2.x + v2.y * v2.y + v2.z * v2.z + v2.w * v2.w;
#pragma unroll
      for (int o = 1; o < 16; o <<= 1) s2 += __shfl_xor(s2, o, 16);
      float inv2 = rsqrtf(s2 * (1.0f / 64.0f) + 1e-6f);
      xn[r2][l * 4 + 0] = v2.x * inv2 * rms_w[l * 4 + 0];
      xn[r2][l * 4 + 1] = v2.y * inv2 * rms_w[l * 4 + 1];
      xn[r2][l * 4 + 2] = v2.z * inv2 * rms_w[l * 4 + 2];
      xn[r2][l * 4 + 3] = v2.w * inv2 * rms_w[l * 4 + 3];
    }
  }
  __syncthreads();
  // GEMM: 19 rows x 296 cols, k=64 (xn broadcast from LDS)
  for (int c = t; c < INW; c += 256) {
    float acc[19];
#pragma unroll
    for (int lr = 0; lr < 19; ++lr) acc[lr] = 0.f;
    const float* Wc = W + c;
    for (int k = 0; k < 64; k += 4) {
      float w0 = Wc[k * INW], w1 = Wc[(k + 1) * INW], w2 = Wc[(k + 2) * INW],
            w3 = Wc[(k + 3) * INW];
#pragma unroll
      for (int lr = 0; lr < 19; ++lr) {
        float4 xv = *(const float4*)&xn[lr][k];
        acc[lr] = fmaf(xv.x, w0, acc[lr]);
        acc[lr] = fmaf(xv.y, w1, acc[lr]);
        acc[lr] = fmaf(xv.z, w2, acc[lr]);
        acc[lr] = fmaf(xv.w, w3, acc[lr]);
      }
    }
    if (c < DI) {
#pragma unroll
      for (int lr = 3; lr < 19; ++lr)
        z[(size_t)(row0 + lr - 3) * DI + c] = acc[lr];
    } else if (c < DI + XBC_) {
#pragma unroll
      for (int lr = 0; lr < 19; ++lr) s_xbc[lr][c - DI] = acc[lr];
    } else {
      int h = c - (DI + XBC_);
      float Ae = __expf(A_log[h]);
      float db = dt_bias[h];
#pragma unroll
      for (int lr = 3; lr < 19; ++lr) {
        float dtr = acc[lr] + db;
        float dt = (dtr > 20.f) ? dtr : log1pf(__expf(dtr));
        float a = __expf(-Ae * dt);
        ahd[(size_t)(row0 + lr - 3) * 8 + h] = make_float2(a, 0.5f * dt);
      }
    }
  }
  __syncthreads();
  // conv + silu (halo rows are exact zeros at sequence start)
  for (int idx = t; idx < 16 * XBC_; idx += 256) {
    int rr = idx / 160, c = idx - rr * 160;
    float acc = conv_b[c];
#pragma unroll
    for (int k = 0; k < CONVK; ++k)
      acc = fmaf(s_xbc[rr + k][c], s_cw[c * 4 + k], acc);
    float s = acc / (1.0f + __expf(-acc));
    if (c < DI)
      xs[(size_t)(row0 + rr) * DI + c] = s;
    else
      bcv[rr][c - DI] = s;
  }
  __syncthreads();
  // RoPE on B and C
  {
    int rr = t >> 4, j = t & 15;
    int row = row0 + rr;
    int tpos = row & (L_ - 1);
    int i = j & 7;
    float invf = exp2f(-(float)i * 1.66096404744368f);  // 10000^(-i/8)
    float ang = (float)tpos * invf;
    float sn = sinf(ang), cs = cosf(ang);
    if (j < 8) {
      float b1 = bcv[rr][i], b2 = bcv[rr][i + 8];
      Bmr[(size_t)row * 16 + i] = b1 * cs - b2 * sn;
      Bmr[(size_t)row * 16 + i + 8] = b1 * sn + b2 * cs;
    } else {
      float c1 = bcv[rr][16 + i], c2 = bcv[rr][24 + i];
      Cmr[(size_t)row * 16 + i] = c1 * cs - c2 * sn;
      Cmr[(size_t)row * 16 + i + 8] = c1 * sn + c2 * cs;
    }
  }
}

// ---------------------------------------------------------------------------
// Kernel C: scan pass 1 — chunk-local end-state only (h0=0).
// One wave per (b,h,chunk), 4 waves/block. lane = p*4+ng.
// ---------------------------------------------------------------------------
__global__ __launch_bounds__(256) void k_state(
    const float* __restrict__ xs, const float* __restrict__ Bmr,
    const float2* __restrict__ ahd, float* __restrict__ hend,
    float* __restrict__ aprod) {
  const int task = blockIdx.x * 4 + (threadIdx.x >> 6);
  const int ck = task & (NCK - 1), bh = task >> 6;
  const int h = bh & 7, b = bh >> 3;
  const int lane = threadIdx.x & 63;
  const int p = lane >> 2, ng = lane & 3;
  const int t0 = ck * CS;
  const int row0 = b * L_ + t0;

  const float* xp = xs + (size_t)row0 * DI + h * 16 + p;
  const float* Bp = Bmr + (size_t)row0 * 16 + ng * 4;
  const float2* ap = ahd + (size_t)row0 * 8 + h;

  float hst[4] = {0.f, 0.f, 0.f, 0.f};
  float bxp[4] = {0.f, 0.f, 0.f, 0.f};
  if (t0 > 0) {
    float xprev = xp[-DI];
    float4 Bq = *(const float4*)(Bp - 16);
    bxp[0] = xprev * Bq.x; bxp[1] = xprev * Bq.y;
    bxp[2] = xprev * Bq.z; bxp[3] = xprev * Bq.w;
  }
  float cum = 1.0f;
  float xv = xp[0];
  float4 Bv = *(const float4*)Bp;
  float2 ah = ap[0];
  for (int i = 0; i < CS - 1; ++i) {
    float xv2 = xp[(size_t)(i + 1) * DI];
    float4 Bv2 = *(const float4*)(Bp + (i + 1) * 16);
    float2 ah2 = ap[(size_t)(i + 1) * 8];
    float av = ah.x, hd = ah.y;
    float Bb[4] = {Bv.x, Bv.y, Bv.z, Bv.w};
#pragma unroll
    for (int j = 0; j < 4; ++j) {
      float bx = xv * Bb[j];
      float t1 = fmaf(hd, bxp[j], hst[j]);
      hst[j] = fmaf(av, t1, hd * bx);
      bxp[j] = bx;
    }
    cum *= av;
    xv = xv2; Bv = Bv2; ah = ah2;
  }
  {
    float av = ah.x, hd = ah.y;
    float Bb[4] = {Bv.x, Bv.y, Bv.z, Bv.w};
#pragma unroll
    for (int j = 0; j < 4; ++j) {
      float bx = xv * Bb[j];
      float t1 = fmaf(hd, bxp[j], hst[j]);
      hst[j] = fmaf(av, t1, hd * bx);
    }
    cum *= av;
  }
  *(float4*)(hend + (size_t)task * 256 + p * 16 + ng * 4) =
      make_float4(hst[0], hst[1], hst[2], hst[3]);
  if (lane == 0) aprod[task] = cum;
}

// ---------------------------------------------------------------------------
// Kernel D: scan pass 2 — chunk combine per (b,h), fully LDS-staged.
// hstart[ck] = exclusive prefix: h-state entering chunk ck.
// ---------------------------------------------------------------------------
__global__ __launch_bounds__(256) void k_scan2(const float* __restrict__ hend,
                                               const float* __restrict__ aprod,
                                               float* __restrict__ hstart) {
  __shared__ float hl[NCK * 256];  // 64 KB
  __shared__ float al[NCK];
  const int bh = blockIdx.x;
  const int t = threadIdx.x;
  const float4* src = (const float4*)(hend + (size_t)bh * NCK * 256);
  for (int i = t; i < NCK * 64; i += 256) ((float4*)hl)[i] = src[i];
  if (t < NCK) al[t] = aprod[bh * NCK + t];
  __syncthreads();
  float* hsp = hstart + (size_t)bh * NCK * 256 + t;
  float hs = 0.f;
  for (int ck = 0; ck < NCK; ++ck) {
    hsp[(size_t)ck * 256] = hs;
    hs = fmaf(al[ck], hs, hl[ck * 256 + t]);
  }
}

// ---------------------------------------------------------------------------
// Kernel E (fused): exact rescan seeded with hstart -> y -> +Dp*xs
//                   -> *silu(z) -> out_proj (128x64) -> residual add.
// One block per (b, chunk): 32 rows. 4 waves; wave w scans heads 2w, 2w+1.
// ---------------------------------------------------------------------------
__global__ __launch_bounds__(256) void k_scanout(
    const float* __restrict__ xs, const float* __restrict__ Bmr,
    const float* __restrict__ Cmr, const float2* __restrict__ ahd,
    const float* __restrict__ hstart, const float* __restrict__ z,
    const float* __restrict__ Dp, const float* __restrict__ W,
    float* __restrict__ x) {
  __shared__ float gy[CS][DI];
  const int ck = blockIdx.x & (NCK - 1);
  const int b = blockIdx.x >> 6;
  const int t = threadIdx.x;
  const int w = t >> 6, lane = t & 63;
  const int p = lane >> 2, ng = lane & 3;
  const int t0 = ck * CS;
  const int row0 = b * L_ + t0;

#pragma unroll
  for (int hh = 0; hh < 2; ++hh) {
    const int h = w * 2 + hh;
    const float* xp = xs + (size_t)row0 * DI + h * 16 + p;
    const float* Bp = Bmr + (size_t)row0 * 16 + ng * 4;
    const float* Cp = Cmr + (size_t)row0 * 16 + ng * 4;
    const float2* ap = ahd + (size_t)row0 * 8 + h;
    float hst[4];
    *(float4*)hst = *(const float4*)(hstart +
        ((size_t)((b * NH + h) * NCK + ck)) * 256 + p * 16 + ng * 4);
    float bxp[4] = {0.f, 0.f, 0.f, 0.f};
    if (t0 > 0) {
      float xprev = xp[-DI];
      float4 Bq = *(const float4*)(Bp - 16);
      bxp[0] = xprev * Bq.x; bxp[1] = xprev * Bq.y;
      bxp[2] = xprev * Bq.z; bxp[3] = xprev * Bq.w;
    }
    const float Dh = Dp[h];
    float xv = xp[0];
    float4 Bv = *(const float4*)Bp;
    float4 Cv = *(const float4*)Cp;
    float2 ah = ap[0];
    for (int i = 0; i < CS; ++i) {
      float xv2 = 0.f; float4 Bv2 = Bv, Cv2 = Cv; float2 ah2 = ah;
      if (i < CS - 1) {
        xv2 = xp[(size_t)(i + 1) * DI];
        Bv2 = *(const float4*)(Bp + (i + 1) * 16);
        Cv2 = *(const float4*)(Cp + (i + 1) * 16);
        ah2 = ap[(size_t)(i + 1) * 8];
      }
      float av = ah.x, hd = ah.y;
      float Bb[4] = {Bv.x, Bv.y, Bv.z, Bv.w};
      float Cb[4] = {Cv.x, Cv.y, Cv.z, Cv.w};
      float y = 0.f;
#pragma unroll
      for (int j = 0; j < 4; ++j) {
        float bx = xv * Bb[j];
        float t1 = fmaf(hd, bxp[j], hst[j]);
        hst[j] = fmaf(av, t1, hd * bx);
        y = fmaf(hst[j], Cb[j], y);
        bxp[j] = bx;
      }
      y += __shfl_xor(y, 1, 64);
      y += __shfl_xor(y, 2, 64);
      if (ng == 0) gy[i][h * 16 + p] = fmaf(Dh, xv, y);
      xv = xv2; Bv = Bv2; Cv = Cv2; ah = ah2;
    }
  }
  __syncthreads();
  // gate with silu(z)
  for (int i = t; i < CS * (DI / 4); i += 256) {
    int rr = i >> 5, c4 = i & 31;
    float4 zv = ((const float4*)(z + (size_t)(row0 + rr) * DI))[c4];
    float4 gv = *(const float4*)&gy[rr][c4 * 4];
    gv.x *= zv.x / (1.0f + __expf(-zv.x));
    gv.y *= zv.y / (1.0f + __expf(-zv.y));
    gv.z *= zv.z / (1.0f + __expf(-zv.z));
    gv.w *= zv.w / (1.0f + __expf(-zv.w));
    *(float4*)&gy[rr][c4 * 4] = gv;
  }
  __syncthreads();
  // out-GEMM 32 rows x 64 cols, k=128; residual add into x
  const int c = t & 63, rg = t >> 6;
  float acc[8];
#pragma unroll
  for (int j = 0; j < 8; ++j) acc[j] = 0.f;
  const float* Wc = W + c;
  for (int k = 0; k < DI; k += 4) {
    float w0 = Wc[k * 64], w1 = Wc[(k + 1) * 64], w2 = Wc[(k + 2) * 64],
          w3 = Wc[(k + 3) * 64];
#pragma unroll
    for (int j = 0; j < 8; ++j) {
      float4 gv = *(const float4*)&gy[rg + j * 4][k];
      acc[j] = fmaf(gv.x, w0, acc[j]);
      acc[j] = fmaf(gv.y, w1, acc[j]);
      acc[j] = fmaf(gv.z, w2, acc[j]);
      acc[j] = fmaf(gv.w, w3, acc[j]);
    }
  }
#pragma unroll
  for (int j = 0; j < 8; ++j) {
    size_t row = row0 + rg + j * 4;
    x[row * 64 + c] += acc[j];
  }
}

// ---------------------------------------------------------------------------
// Kernel F: final LayerNorm + head (64 x 6) + bias -> out (BL, 6)
// ---------------------------------------------------------------------------
__global__ __launch_bounds__(256) void k_head(
    const float* __restrict__ x, const float* __restrict__ ln_g,
    const float* __restrict__ ln_b, const float* __restrict__ W,
    const float* __restrict__ bias, float* __restrict__ out) {
  __shared__ float xn[4][64];
  const int t = threadIdx.x;
  const int r = t >> 6, k = t & 63;
  const int row = blockIdx.x * 4 + r;
  float v = x[(size_t)row * 64 + k];
  float mu = v;
#pragma unroll
  for (int o = 1; o < 64; o <<= 1) mu += __shfl_xor(mu, o, 64);
  mu *= (1.0f / 64.0f);
  float d = v - mu;
  float var = d * d;
#pragma unroll
  for (int o = 1; o < 64; o <<= 1) var += __shfl_xor(var, o, 64);
  var *= (1.0f / 64.0f);
  xn[r][k] = d * rsqrtf(var + 1e-5f) * ln_g[k] + ln_b[k];
  __syncthreads();
  if (k < NACT) {
    float acc = bias[k];
    for (int kk = 0; kk < 64; ++kk) acc = fmaf(xn[r][kk], W[kk * NACT + k], acc);
    out[(size_t)row * NACT + k] = acc;
  }
}

// ---------------------------------------------------------------------------
extern "C" void kernel_launch(void* const* d_in, const int* in_sizes, int n_in,
                              void* d_out, int out_size, void* d_ws,
                              size_t ws_size, hipStream_t stream) {
  const int* aggs = (const int*)d_in[0];
  const float* pegE = (const float*)d_in[1];
  const float* countE = (const float*)d_in[2];
  const float* topE = (const float*)d_in[3];
  const float* proj_in_w = (const float*)d_in[4];
  const float* proj_in_b = (const float*)d_in[5];
  const float* rms_w = (const float*)d_in[6];
  const float* in_w = (const float*)d_in[7];
  const float* conv_w = (const float*)d_in[8];
  const float* conv_b = (const float*)d_in[9];
  const float* dt_bias = (const float*)d_in[10];
  const float* A_log = (const float*)d_in[11];
  const float* Dp = (const float*)d_in[12];
  const float* outp_w = (const float*)d_in[13];
  const float* ln_g = (const float*)d_in[14];
  const float* ln_b = (const float*)d_in[15];
  const float* out_w = (const float*)d_in[16];
  const float* out_b = (const float*)d_in[17];
  float* out = (float*)d_out;

  float* ws = (float*)d_ws;
  size_t off = 0;
  float* x = ws + off;      off += (size_t)BL * 64;
  float* z = ws + off;      off += (size_t)BL * DI;
  float* xs = ws + off;     off += (size_t)BL * DI;
  float* Bmr = ws + off;    off += (size_t)BL * 16;
  float* Cmr = ws + off;    off += (size_t)BL * 16;
  float2* ahd = (float2*)(ws + off); off += (size_t)BL * 16;
  float* hend = ws + off;   off += (size_t)B_ * NH * NCK * 256;
  float* aprod = ws + off;  off += (size_t)B_ * NH * NCK;
  float* hstart = ws + off; off += (size_t)B_ * NH * NCK * 256;

  k_embed<<<BL / 16, 256, 0, stream>>>(aggs, pegE, countE, topE, proj_in_w,
                                       proj_in_b, x);
  for (int l = 0; l < 2; ++l) {
    k_fused_in<<<BL / 16, 256, 0, stream>>>(
        x, rms_w + l * 64, in_w + (size_t)l * 64 * INW, conv_w + l * XBC_ * 4,
        conv_b + l * XBC_, dt_bias + l * 8, A_log + l * 8, z, xs, Bmr, Cmr,
        ahd);
    k_state<<<B_ * NH * NCK / 4, 256, 0, stream>>>(xs, Bmr, ahd, hend, aprod);
    k_scan2<<<B_ * NH, 256, 0, stream>>>(hend, aprod, hstart);
    k_scanout<<<B_ * NCK, 256, 0, stream>>>(xs, Bmr, Cmr, ahd, hstart, z,
                                            Dp + l * 8,
                                            outp_w + (size_t)l * 128 * 64, x);
  }
  k_head<<<BL / 4, 256, 0, stream>>>(x, ln_g, ln_b, out_w, out_b, out);
}

// Round 8
// 373.730 us; speedup vs baseline: 1.2719x; 1.2719x over previous
//
#include <hip/hip_runtime.h>
#include <hip/hip_bf16.h>

#define B_    16
#define L_    2048
#define BL    (B_ * L_)
#define DM    64
#define DS    16
#define HD    16
#define DI    128
#define NH    8
#define INW   296
#define XBC_  160
#define CONVK 4
#define NAGG  10
#define NACT  6
#define CS    32          // chunk size for scan
#define NCK   (L_ / CS)   // 64 chunks

// ---------------------------------------------------------------------------
// Kernel A: embedding gather + proj_in (80 x 64) + bias -> x (BL, 64)
// ---------------------------------------------------------------------------
__global__ __launch_bounds__(256) void k_embed(
    const int* __restrict__ aggs, const float* __restrict__ pegE,
    const float* __restrict__ countE, const float* __restrict__ topE,
    const float* __restrict__ W, const float* __restrict__ bias,
    float* __restrict__ x) {
  __shared__ float e[16][80];
  const int row0 = blockIdx.x * 16;
  const int t = threadIdx.x;
  if (t < 160) {
    int r = t / 10, i = t % 10;
    const float* tab = (i == 0 || i == 1 || i == 9) ? pegE
                       : (i >= 5 && i <= 7)         ? topE
                                                    : countE;
    int idx = aggs[(row0 + r) * NAGG + i];
    const float* src = tab + idx * 8;
#pragma unroll
    for (int j = 0; j < 8; ++j) e[r][i * 8 + j] = src[j];
  }
  __syncthreads();
  const int c = t & 63, rg = t >> 6;
  float acc[4] = {0.f, 0.f, 0.f, 0.f};
  const float* Wc = W + c;
  for (int k = 0; k < 80; k += 4) {
    float w0 = Wc[k * 64], w1 = Wc[(k + 1) * 64], w2 = Wc[(k + 2) * 64],
          w3 = Wc[(k + 3) * 64];
#pragma unroll
    for (int j = 0; j < 4; ++j) {
      float4 ev = *(const float4*)&e[rg + j * 4][k];
      acc[j] = fmaf(ev.x, w0, acc[j]);
      acc[j] = fmaf(ev.y, w1, acc[j]);
      acc[j] = fmaf(ev.z, w2, acc[j]);
      acc[j] = fmaf(ev.w, w3, acc[j]);
    }
  }
  float bc = bias[c];
#pragma unroll
  for (int j = 0; j < 4; ++j) x[(size_t)(row0 + rg + j * 4) * 64 + c] = acc[j] + bc;
}

// ---------------------------------------------------------------------------
// Kernel B (fused): RMSNorm + in_proj (64x296) + causal conv(K=4) + SiLU
//                   + RoPE + dt/a precompute.  16 out rows, 19-row halo.
// ---------------------------------------------------------------------------
__global__ __launch_bounds__(256, 4) void k_fused_in(
    const float* __restrict__ x, const float* __restrict__ rms_w,
    const float* __restrict__ W, const float* __restrict__ conv_w,
    const float* __restrict__ conv_b, const float* __restrict__ dt_bias,
    const float* __restrict__ A_log, float* __restrict__ z,
    float* __restrict__ xs, float* __restrict__ Bmr, float* __restrict__ Cmr,
    float2* __restrict__ ahd) {
  __shared__ float xn[19][64];
  __shared__ float s_xbc[19][160];
  __shared__ float s_cw[640];
  __shared__ float bcv[16][32];
  const int row0 = blockIdx.x * 16;
  const int t = threadIdx.x;
  const bool atStart = (row0 & (L_ - 1)) == 0;
  for (int idx = t; idx < 19 * 64; idx += 256) {
    int lr = idx >> 6, c = idx & 63;
    xn[lr][c] = (atStart && lr < 3) ? 0.f
                                    : x[(size_t)(row0 + lr - 3) * 64 + c];
  }
  for (int idx = t; idx < 640; idx += 256) s_cw[idx] = conv_w[idx];
  __syncthreads();
  // RMSNorm in place: 16 threads per row
  {
    int r = t >> 4, l = t & 15;
    float4 v = *(const float4*)&xn[r][l * 4];
    float ss = v.x * v.x + v.y * v.y + v.z * v.z + v.w * v.w;
#pragma unroll
    for (int o = 1; o < 16; o <<= 1) ss += __shfl_xor(ss, o, 16);
    float inv = rsqrtf(ss * (1.0f / 64.0f) + 1e-6f);
    xn[r][l * 4 + 0] = v.x * inv * rms_w[l * 4 + 0];
    xn[r][l * 4 + 1] = v.y * inv * rms_w[l * 4 + 1];
    xn[r][l * 4 + 2] = v.z * inv * rms_w[l * 4 + 2];
    xn[r][l * 4 + 3] = v.w * inv * rms_w[l * 4 + 3];
    if (t < 48) {  // rows 16..18
      int r2 = 16 + (t >> 4);
      float4 v2 = *(const float4*)&xn[r2][l * 4];
      float s2 = v2.x * v2.x + v2.y * v2.y + v2.z * v2.z + v2.w * v2.w;
#pragma unroll
      for (int o = 1; o < 16; o <<= 1) s2 += __shfl_xor(s2, o, 16);
      float inv2 = rsqrtf(s2 * (1.0f / 64.0f) + 1e-6f);
      xn[r2][l * 4 + 0] = v2.x * inv2 * rms_w[l * 4 + 0];
      xn[r2][l * 4 + 1] = v2.y * inv2 * rms_w[l * 4 + 1];
      xn[r2][l * 4 + 2] = v2.z * inv2 * rms_w[l * 4 + 2];
      xn[r2][l * 4 + 3] = v2.w * inv2 * rms_w[l * 4 + 3];
    }
  }
  __syncthreads();
  // GEMM: 19 rows x 296 cols, k=64
  for (int c = t; c < INW; c += 256) {
    float acc[19];
#pragma unroll
    for (int lr = 0; lr < 19; ++lr) acc[lr] = 0.f;
    const float* Wc = W + c;
    for (int k = 0; k < 64; k += 4) {
      float w0 = Wc[k * INW], w1 = Wc[(k + 1) * INW], w2 = Wc[(k + 2) * INW],
            w3 = Wc[(k + 3) * INW];
#pragma unroll
      for (int lr = 0; lr < 19; ++lr) {
        float4 xv = *(const float4*)&xn[lr][k];
        acc[lr] = fmaf(xv.x, w0, acc[lr]);
        acc[lr] = fmaf(xv.y, w1, acc[lr]);
        acc[lr] = fmaf(xv.z, w2, acc[lr]);
        acc[lr] = fmaf(xv.w, w3, acc[lr]);
      }
    }
    if (c < DI) {
#pragma unroll
      for (int lr = 3; lr < 19; ++lr)
        z[(size_t)(row0 + lr - 3) * DI + c] = acc[lr];
    } else if (c < DI + XBC_) {
#pragma unroll
      for (int lr = 0; lr < 19; ++lr) s_xbc[lr][c - DI] = acc[lr];
    } else {
      int h = c - (DI + XBC_);
      float Ae = __expf(A_log[h]);
      float db = dt_bias[h];
#pragma unroll
      for (int lr = 3; lr < 19; ++lr) {
        float dtr = acc[lr] + db;
        float dt = (dtr > 20.f) ? dtr : log1pf(__expf(dtr));
        float a = __expf(-Ae * dt);
        ahd[(size_t)(row0 + lr - 3) * 8 + h] = make_float2(a, 0.5f * dt);
      }
    }
  }
  __syncthreads();
  // conv + silu
  for (int idx = t; idx < 16 * XBC_; idx += 256) {
    int rr = idx / 160, c = idx - rr * 160;
    float acc = conv_b[c];
#pragma unroll
    for (int k = 0; k < CONVK; ++k)
      acc = fmaf(s_xbc[rr + k][c], s_cw[c * 4 + k], acc);
    float s = acc / (1.0f + __expf(-acc));
    if (c < DI)
      xs[(size_t)(row0 + rr) * DI + c] = s;
    else
      bcv[rr][c - DI] = s;
  }
  __syncthreads();
  // RoPE on B and C
  {
    int rr = t >> 4, j = t & 15;
    int row = row0 + rr;
    int tpos = row & (L_ - 1);
    int i = j & 7;
    float invf = exp2f(-(float)i * 1.66096404744368f);  // 10000^(-i/8)
    float ang = (float)tpos * invf;
    float sn = sinf(ang), cs = cosf(ang);
    if (j < 8) {
      float b1 = bcv[rr][i], b2 = bcv[rr][i + 8];
      Bmr[(size_t)row * 16 + i] = b1 * cs - b2 * sn;
      Bmr[(size_t)row * 16 + i + 8] = b1 * sn + b2 * cs;
    } else {
      float c1 = bcv[rr][16 + i], c2 = bcv[rr][24 + i];
      Cmr[(size_t)row * 16 + i] = c1 * cs - c2 * sn;
      Cmr[(size_t)row * 16 + i + 8] = c1 * sn + c2 * cs;
    }
  }
}

// ---------------------------------------------------------------------------
// Kernel C: scan pass 1 — chunk-local end-state only (h0=0).
// ---------------------------------------------------------------------------
__global__ __launch_bounds__(256) void k_state(
    const float* __restrict__ xs, const float* __restrict__ Bmr,
    const float2* __restrict__ ahd, float* __restrict__ hend,
    float* __restrict__ aprod) {
  const int task = blockIdx.x * 4 + (threadIdx.x >> 6);
  const int ck = task & (NCK - 1), bh = task >> 6;
  const int h = bh & 7, b = bh >> 3;
  const int lane = threadIdx.x & 63;
  const int p = lane >> 2, ng = lane & 3;
  const int t0 = ck * CS;
  const int row0 = b * L_ + t0;

  const float* xp = xs + (size_t)row0 * DI + h * 16 + p;
  const float* Bp = Bmr + (size_t)row0 * 16 + ng * 4;
  const float2* ap = ahd + (size_t)row0 * 8 + h;

  float hst[4] = {0.f, 0.f, 0.f, 0.f};
  float bxp[4] = {0.f, 0.f, 0.f, 0.f};
  if (t0 > 0) {
    float xprev = xp[-DI];
    float4 Bq = *(const float4*)(Bp - 16);
    bxp[0] = xprev * Bq.x; bxp[1] = xprev * Bq.y;
    bxp[2] = xprev * Bq.z; bxp[3] = xprev * Bq.w;
  }
  float cum = 1.0f;
  float xv = xp[0];
  float4 Bv = *(const float4*)Bp;
  float2 ah = ap[0];
  for (int i = 0; i < CS - 1; ++i) {
    float xv2 = xp[(size_t)(i + 1) * DI];
    float4 Bv2 = *(const float4*)(Bp + (i + 1) * 16);
    float2 ah2 = ap[(size_t)(i + 1) * 8];
    float av = ah.x, hd = ah.y;
    float Bb[4] = {Bv.x, Bv.y, Bv.z, Bv.w};
#pragma unroll
    for (int j = 0; j < 4; ++j) {
      float bx = xv * Bb[j];
      float t1 = fmaf(hd, bxp[j], hst[j]);
      hst[j] = fmaf(av, t1, hd * bx);
      bxp[j] = bx;
    }
    cum *= av;
    xv = xv2; Bv = Bv2; ah = ah2;
  }
  {
    float av = ah.x, hd = ah.y;
    float Bb[4] = {Bv.x, Bv.y, Bv.z, Bv.w};
#pragma unroll
    for (int j = 0; j < 4; ++j) {
      float bx = xv * Bb[j];
      float t1 = fmaf(hd, bxp[j], hst[j]);
      hst[j] = fmaf(av, t1, hd * bx);
    }
    cum *= av;
  }
  *(float4*)(hend + (size_t)task * 256 + p * 16 + ng * 4) =
      make_float4(hst[0], hst[1], hst[2], hst[3]);
  if (lane == 0) aprod[task] = cum;
}

// ---------------------------------------------------------------------------
// Kernel D: scan pass 2 — chunk combine per (b,h), fully LDS-staged.
// ---------------------------------------------------------------------------
__global__ __launch_bounds__(256) void k_scan2(const float* __restrict__ hend,
                                               const float* __restrict__ aprod,
                                               float* __restrict__ hstart) {
  __shared__ float hl[NCK * 256];  // 64 KB
  __shared__ float al[NCK];
  const int bh = blockIdx.x;
  const int t = threadIdx.x;
  const float4* src = (const float4*)(hend + (size_t)bh * NCK * 256);
  for (int i = t; i < NCK * 64; i += 256) ((float4*)hl)[i] = src[i];
  if (t < NCK) al[t] = aprod[bh * NCK + t];
  __syncthreads();
  float* hsp = hstart + (size_t)bh * NCK * 256 + t;
  float hs = 0.f;
  for (int ck = 0; ck < NCK; ++ck) {
    hsp[(size_t)ck * 256] = hs;
    hs = fmaf(al[ck], hs, hl[ck * 256 + t]);
  }
}

// ---------------------------------------------------------------------------
// Kernel E (fused): exact rescan seeded with hstart -> y -> +Dp*xs
//                   -> *silu(z) -> out_proj (128x64) -> residual add.
// 512 threads = 8 waves; wave w scans head w (ONE scan state per wave).
// ---------------------------------------------------------------------------
__global__ __launch_bounds__(512, 4) void k_scanout(
    const float* __restrict__ xs, const float* __restrict__ Bmr,
    const float* __restrict__ Cmr, const float2* __restrict__ ahd,
    const float* __restrict__ hstart, const float* __restrict__ z,
    const float* __restrict__ Dp, const float* __restrict__ W,
    float* __restrict__ x) {
  __shared__ float gy[CS][DI];
  const int ck = blockIdx.x & (NCK - 1);
  const int b = blockIdx.x >> 6;
  const int t = threadIdx.x;
  const int h = t >> 6;  // wave id == head
  const int lane = t & 63;
  const int p = lane >> 2, ng = lane & 3;
  const int t0 = ck * CS;
  const int row0 = b * L_ + t0;

  {
    const float* xp = xs + (size_t)row0 * DI + h * 16 + p;
    const float* Bp = Bmr + (size_t)row0 * 16 + ng * 4;
    const float* Cp = Cmr + (size_t)row0 * 16 + ng * 4;
    const float2* ap = ahd + (size_t)row0 * 8 + h;
    float hst[4];
    *(float4*)hst = *(const float4*)(hstart +
        ((size_t)((b * NH + h) * NCK + ck)) * 256 + p * 16 + ng * 4);
    float bxp[4] = {0.f, 0.f, 0.f, 0.f};
    if (t0 > 0) {
      float xprev = xp[-DI];
      float4 Bq = *(const float4*)(Bp - 16);
      bxp[0] = xprev * Bq.x; bxp[1] = xprev * Bq.y;
      bxp[2] = xprev * Bq.z; bxp[3] = xprev * Bq.w;
    }
    const float Dh = Dp[h];
    float xv = xp[0];
    float4 Bv = *(const float4*)Bp;
    float4 Cv = *(const float4*)Cp;
    float2 ah = ap[0];
    for (int i = 0; i < CS - 1; ++i) {
      // prefetch next step (independent of serial chain)
      float xv2 = xp[(size_t)(i + 1) * DI];
      float4 Bv2 = *(const float4*)(Bp + (i + 1) * 16);
      float4 Cv2 = *(const float4*)(Cp + (i + 1) * 16);
      float2 ah2 = ap[(size_t)(i + 1) * 8];
      float av = ah.x, hd = ah.y;
      float y = 0.f;
#pragma unroll
      for (int j = 0; j < 4; ++j) {
        float Bj = (j == 0) ? Bv.x : (j == 1) ? Bv.y : (j == 2) ? Bv.z : Bv.w;
        float Cj = (j == 0) ? Cv.x : (j == 1) ? Cv.y : (j == 2) ? Cv.z : Cv.w;
        float bx = xv * Bj;
        float t1 = fmaf(hd, bxp[j], hst[j]);
        hst[j] = fmaf(av, t1, hd * bx);
        y = fmaf(hst[j], Cj, y);
        bxp[j] = bx;
      }
      y += __shfl_xor(y, 1, 64);
      y += __shfl_xor(y, 2, 64);
      if (ng == 0) gy[i][h * 16 + p] = fmaf(Dh, xv, y);
      xv = xv2; Bv = Bv2; Cv = Cv2; ah = ah2;
    }
    {  // peeled last step
      float av = ah.x, hd = ah.y;
      float y = 0.f;
#pragma unroll
      for (int j = 0; j < 4; ++j) {
        float Bj = (j == 0) ? Bv.x : (j == 1) ? Bv.y : (j == 2) ? Bv.z : Bv.w;
        float Cj = (j == 0) ? Cv.x : (j == 1) ? Cv.y : (j == 2) ? Cv.z : Cv.w;
        float bx = xv * Bj;
        float t1 = fmaf(hd, bxp[j], hst[j]);
        hst[j] = fmaf(av, t1, hd * bx);
        y = fmaf(hst[j], Cj, y);
      }
      y += __shfl_xor(y, 1, 64);
      y += __shfl_xor(y, 2, 64);
      if (ng == 0) gy[CS - 1][h * 16 + p] = fmaf(Dh, xv, y);
    }
  }
  __syncthreads();
  // gate with silu(z): 1024 float4 elems, 512 threads -> 2 iters
  for (int i = t; i < CS * (DI / 4); i += 512) {
    int rr = i >> 5, c4 = i & 31;
    float4 zv = ((const float4*)(z + (size_t)(row0 + rr) * DI))[c4];
    float4 gv = *(const float4*)&gy[rr][c4 * 4];
    gv.x *= zv.x / (1.0f + __expf(-zv.x));
    gv.y *= zv.y / (1.0f + __expf(-zv.y));
    gv.z *= zv.z / (1.0f + __expf(-zv.z));
    gv.w *= zv.w / (1.0f + __expf(-zv.w));
    *(float4*)&gy[rr][c4 * 4] = gv;
  }
  __syncthreads();
  // out-GEMM 32 rows x 64 cols, k=128; rows rg, rg+8, rg+16, rg+24
  const int c = t & 63, rg = t >> 6;
  float acc[4] = {0.f, 0.f, 0.f, 0.f};
  const float* Wc = W + c;
  for (int k = 0; k < DI; k += 4) {
    float w0 = Wc[k * 64], w1 = Wc[(k + 1) * 64], w2 = Wc[(k + 2) * 64],
          w3 = Wc[(k + 3) * 64];
#pragma unroll
    for (int j = 0; j < 4; ++j) {
      float4 gv = *(const float4*)&gy[rg + j * 8][k];
      acc[j] = fmaf(gv.x, w0, acc[j]);
      acc[j] = fmaf(gv.y, w1, acc[j]);
      acc[j] = fmaf(gv.z, w2, acc[j]);
      acc[j] = fmaf(gv.w, w3, acc[j]);
    }
  }
#pragma unroll
  for (int j = 0; j < 4; ++j) {
    size_t row = row0 + rg + j * 8;
    x[row * 64 + c] += acc[j];
  }
}

// ---------------------------------------------------------------------------
// Kernel F: final LayerNorm + head (64 x 6) + bias -> out (BL, 6)
// ---------------------------------------------------------------------------
__global__ __launch_bounds__(256) void k_head(
    const float* __restrict__ x, const float* __restrict__ ln_g,
    const float* __restrict__ ln_b, const float* __restrict__ W,
    const float* __restrict__ bias, float* __restrict__ out) {
  __shared__ float xn[4][64];
  const int t = threadIdx.x;
  const int r = t >> 6, k = t & 63;
  const int row = blockIdx.x * 4 + r;
  float v = x[(size_t)row * 64 + k];
  float mu = v;
#pragma unroll
  for (int o = 1; o < 64; o <<= 1) mu += __shfl_xor(mu, o, 64);
  mu *= (1.0f / 64.0f);
  float d = v - mu;
  float var = d * d;
#pragma unroll
  for (int o = 1; o < 64; o <<= 1) var += __shfl_xor(var, o, 64);
  var *= (1.0f / 64.0f);
  xn[r][k] = d * rsqrtf(var + 1e-5f) * ln_g[k] + ln_b[k];
  __syncthreads();
  if (k < NACT) {
    float acc = bias[k];
    for (int kk = 0; kk < 64; ++kk) acc = fmaf(xn[r][kk], W[kk * NACT + k], acc);
    out[(size_t)row * NACT + k] = acc;
  }
}

// ---------------------------------------------------------------------------
extern "C" void kernel_launch(void* const* d_in, const int* in_sizes, int n_in,
                              void* d_out, int out_size, void* d_ws,
                              size_t ws_size, hipStream_t stream) {
  const int* aggs = (const int*)d_in[0];
  const float* pegE = (const float*)d_in[1];
  const float* countE = (const float*)d_in[2];
  const float* topE = (const float*)d_in[3];
  const float* proj_in_w = (const float*)d_in[4];
  const float* proj_in_b = (const float*)d_in[5];
  const float* rms_w = (const float*)d_in[6];
  const float* in_w = (const float*)d_in[7];
  const float* conv_w = (const float*)d_in[8];
  const float* conv_b = (const float*)d_in[9];
  const float* dt_bias = (const float*)d_in[10];
  const float* A_log = (const float*)d_in[11];
  const float* Dp = (const float*)d_in[12];
  const float* outp_w = (const float*)d_in[13];
  const float* ln_g = (const float*)d_in[14];
  const float* ln_b = (const float*)d_in[15];
  const float* out_w = (const float*)d_in[16];
  const float* out_b = (const float*)d_in[17];
  float* out = (float*)d_out;

  float* ws = (float*)d_ws;
  size_t off = 0;
  float* x = ws + off;      off += (size_t)BL * 64;
  float* z = ws + off;      off += (size_t)BL * DI;
  float* xs = ws + off;     off += (size_t)BL * DI;
  float* Bmr = ws + off;    off += (size_t)BL * 16;
  float* Cmr = ws + off;    off += (size_t)BL * 16;
  float2* ahd = (float2*)(ws + off); off += (size_t)BL * 16;
  float* hend = ws + off;   off += (size_t)B_ * NH * NCK * 256;
  float* aprod = ws + off;  off += (size_t)B_ * NH * NCK;
  float* hstart = ws + off; off += (size_t)B_ * NH * NCK * 256;

  k_embed<<<BL / 16, 256, 0, stream>>>(aggs, pegE, countE, topE, proj_in_w,
                                       proj_in_b, x);
  for (int l = 0; l < 2; ++l) {
    k_fused_in<<<BL / 16, 256, 0, stream>>>(
        x, rms_w + l * 64, in_w + (size_t)l * 64 * INW, conv_w + l * XBC_ * 4,
        conv_b + l * XBC_, dt_bias + l * 8, A_log + l * 8, z, xs, Bmr, Cmr,
        ahd);
    k_state<<<B_ * NH * NCK / 4, 256, 0, stream>>>(xs, Bmr, ahd, hend, aprod);
    k_scan2<<<B_ * NH, 256, 0, stream>>>(hend, aprod, hstart);
    k_scanout<<<B_ * NCK, 512, 0, stream>>>(xs, Bmr, Cmr, ahd, hstart, z,
                                            Dp + l * 8,
                                            outp_w + (size_t)l * 128 * 64, x);
  }
  k_head<<<BL / 4, 256, 0, stream>>>(x, ln_g, ln_b, out_w, out_b, out);
}